// Round 20
// baseline (549.266 us; speedup 1.0000x reference)
//
#include <hip/hip_runtime.h>

// Problem constants
#define BATCH 32
#define HIN 224
#define WIN 224
#define KCH 64
#define KS 7
#define OH 218
#define OW 218

// Round 18: BARRIER-FREE channel loop (per-wave otile slices).
// r17 (249us): VALUBusy 46%, FMA floor 29% -> 54% of cycles idle; 2 barriers x
// 8 channels serialize the 4 waves' phases at 2 blocks/CU. The otile coupling is
// false: each wave owns rows 8wv..8wv+7 = 6976 B (≡0 mod 64), so each wave can
// copy out its OWN slice with the same phase shift m = W0&15 (slice starts share
// the plane's 64B phase). Channel loop now has ZERO __syncthreads: intra-wave
// DS ordering + reg deps give correctness; waves drift and overlap VALU/LDS/HBM.
// Cost: ~1 partial 64B line per wave boundary (~4 MB total fetch, negligible).
// Compute (input-row-major, r13) and staging identical to r17.
#define TILE_H 32
#define IN_TILE_H 38      // TILE_H + 6
#define LDS_STRIDE 240    // 4 leading zero-pad floats + 236 staged cols
#define CH_PER_BLOCK 8
#define NBANDS 7          // 7*32 = 224 >= 218
#define WAVE_TILE_F (8 * OW)   // 1744 floats = 6976 B per wave slice

typedef float f32x4 __attribute__((ext_vector_type(4)));

__global__ __launch_bounds__(256, 2)
void conv7x7_kernel(const float* __restrict__ x,
                    const float* __restrict__ kern,
                    float* __restrict__ out) {
    __shared__ float tile[IN_TILE_H][LDS_STRIDE];   // 36,480 B
    __shared__ float otile[4][WAVE_TILE_F];         // 27,904 B (total 64,384 B)

    const int band = blockIdx.x;          // 0..6
    const int kg   = blockIdx.y;          // 0..7
    const int b    = blockIdx.z;          // 0..31

    const int h0 = band * TILE_H;

    const int tid  = threadIdx.x;         // 0..255
    const int wv   = tid >> 6;            // wave 0..3
    const int lane = tid & 63;

    // ---- zero the 4-float leading pad (read by odd-row left-edge lanes) ----
    if (tid < IN_TILE_H) {
        f32x4 z = {0.f, 0.f, 0.f, 0.f};
        *reinterpret_cast<f32x4*>(&tile[tid][0]) = z;
    }

    // ---- stage input band: rows h0..h0+37, cols 0..235 at tile[r][4+col] ----
    const float* xb = x + b * (HIN * WIN);
    const int NV = (LDS_STRIDE - 4) / 4;  // 59 float4 per row
    for (int idx = tid; idx < IN_TILE_H * NV; idx += 256) {
        const int r  = idx / NV;
        const int cg = idx - r * NV;
        const int sr = h0 + r;
        const int sc = cg * 4;
        float4 v;
        if (sr < HIN && sc + 3 < WIN) {
            v = *reinterpret_cast<const float4*>(xb + sr * WIN + sc);
        } else {
            float t0 = (sr < HIN && sc + 0 < WIN) ? xb[sr * WIN + sc + 0] : 0.f;
            float t1 = (sr < HIN && sc + 1 < WIN) ? xb[sr * WIN + sc + 1] : 0.f;
            float t2 = (sr < HIN && sc + 2 < WIN) ? xb[sr * WIN + sc + 2] : 0.f;
            float t3 = (sr < HIN && sc + 3 < WIN) ? xb[sr * WIN + sc + 3] : 0.f;
            v = make_float4(t0, t1, t2, t3);
        }
        *reinterpret_cast<float4*>(&tile[r][4 + sc]) = v;
    }
    __syncthreads();                      // the ONLY block-wide barrier

    const int r0  = wv * 8;                         // first out-row within band (even)
    const int hw0 = h0 + r0;                        // this wave's first global row
    const int cl  = (lane < 54) ? lane : 54;        // clamp idle lanes (broadcast reads)
    const int c0  = cl * 4;

    // this wave's valid output floats (band 6 wave 3: 2 rows)
    int rowsv = OH - hw0;
    rowsv = rowsv < 0 ? 0 : (rowsv > 8 ? 8 : rowsv);
    const int Lw = rowsv * OW;

    float* os = &otile[wv][0];

    #pragma unroll 1
    for (int kk = 0; kk < CH_PER_BLOCK; ++kk) {
        const int k = kg * CH_PER_BLOCK + kk;
        const float* __restrict__ wk = kern + k * (KS * KS);  // wave-uniform -> s_load

        f32x4 acc[8];
        #pragma unroll
        for (int i = 0; i < 8; ++i) {
            f32x4 z = {0.f, 0.f, 0.f, 0.f};
            acc[i] = z;
        }

        // ---- input-row-major: load window once, feed all live output rows ----
        #pragma unroll
        for (int ii = 0; ii < 14; ++ii) {
            const float* rp = &tile[r0 + ii][0];
            const f32x4 w0 = *reinterpret_cast<const f32x4*>(rp + c0);
            const f32x4 w1 = *reinterpret_cast<const f32x4*>(rp + c0 + 4);
            const f32x4 w2 = *reinterpret_cast<const f32x4*>(rp + c0 + 8);
            const f32x4 w3 = *reinterpret_cast<const f32x4*>(rp + c0 + 12);

            #pragma unroll
            for (int i = 0; i < 8; ++i) {
                const int ki = ii - i;                 // folds per (ii,i)
                if (ki >= 0 && ki < 7) {
                    const int sh = (i & 1) ? 2 : 4;    // odd rows shifted -2
                    #pragma unroll
                    for (int kj = 0; kj < 7; ++kj) {
                        const float wgt = wk[ki * 7 + kj];
                        #pragma unroll
                        for (int j = 0; j < 4; ++j) {
                            const int n = sh + kj + j;   // constant: 2..13
                            const float xv = (n < 4)  ? w0[n]
                                           : (n < 8)  ? w1[n - 4]
                                           : (n < 12) ? w2[n - 8]
                                                      : w3[n - 12];
                            acc[i][j] = fmaf(wgt, xv, acc[i][j]);
                        }
                    }
                }
            }
        }

        // ---- write rows into THIS WAVE's otile slice (no cross-wave sharing) ----
        #pragma unroll
        for (int i = 0; i < 8; ++i) {
            const int ot = i * OW;
            if ((i & 1) == 0) {
                if (lane < 54) {
                    *reinterpret_cast<f32x4*>(&os[ot + c0]) = acc[i];
                } else if (lane == 54) {
                    os[ot + 216] = acc[i][0];
                    os[ot + 217] = acc[i][1];
                }
            } else {
                if (lane == 0) {
                    os[ot]     = acc[i][2];
                    os[ot + 1] = acc[i][3];
                } else if (lane <= 54) {
                    *reinterpret_cast<f32x4*>(&os[ot + c0 - 2]) = acc[i];
                }
            }
        }
        // no barrier: intra-wave DS ordering guarantees write -> read below

        // ---- per-wave aligned copy-out: lane 0's chunk starts on a 64B line ----
        // W0 mod 4 floats == 0 always; m in {0,4,8,12}. g ≡ 0 mod 4 and
        // Lw ≡ 0 mod 4  =>  g<Lw implies g+4<=Lw (no tail split needed).
        const size_t W0 = (size_t)(b * KCH + k) * (OH * OW) + (size_t)hw0 * OW;
        const int   m   = (int)(W0 & 15);
        float* gbase = out + W0;

        #pragma unroll 1
        for (int g = lane * 4 - m; g < Lw; g += 256) {
            if (g >= 0) {
                *reinterpret_cast<f32x4*>(gbase + g) =
                    *reinterpret_cast<const f32x4*>(&os[g]);
            }
        }
        // no barrier: next channel's otile writes are same-wave, in-order
    }
}

extern "C" void kernel_launch(void* const* d_in, const int* in_sizes, int n_in,
                              void* d_out, int out_size, void* d_ws, size_t ws_size,
                              hipStream_t stream) {
    const float* x    = (const float*)d_in[0];   // (32,224,224) f32
    const float* kern = (const float*)d_in[1];   // (64,7,7) f32
    float* out        = (float*)d_out;           // (32,64,218,218) f32

    dim3 grid(NBANDS, KCH / CH_PER_BLOCK, BATCH); // 7 x 8 x 32 = 1792 blocks
    dim3 block(256, 1, 1);
    conv7x7_kernel<<<grid, block, 0, stream>>>(x, kern, out);
}